// Round 7
// baseline (2745.530 us; speedup 1.0000x reference)
//
#include <hip/hip_runtime.h>
#include <hip/hip_bf16.h>
#include <cmath>

#define D_MODEL 128
#define NUM_HEAD 4
#define HEAD_DIM 32
#define SEQ 4096
#define BATCH 2
#define QTILE 128  // q-rows per attention block (64 lanes x G=2)
#define NW 8       // waves per attention block (k-split factor)
#define CHUNK 8    // k's per softmax-rescale chunk
#define RROWS 32   // token rows per projection block

__device__ __forceinline__ float tof(float x) { return x; }
__device__ __forceinline__ float tof(__hip_bfloat16 x) { return __bfloat162float(x); }
__device__ __forceinline__ void storef(float* p, size_t i, float v) { p[i] = v; }
__device__ __forceinline__ void storef(__hip_bfloat16* p, size_t i, float v) { p[i] = __float2bfloat16(v); }

// ---------------------------------------------------------------------------
// Kernel 0: dtype detector (f32 vs bf16 inputs), unchanged (R3/R5/R6 passed).
// ---------------------------------------------------------------------------
__global__ void detect_kernel(const unsigned short* __restrict__ w, int* __restrict__ flag)
{
    const int t = threadIdx.x;   // 64 threads
    int weird = 0;
#pragma unroll
    for (int j = 0; j < 4; ++j) {
        const unsigned short v = w[(t * 4 + j) * 2 + 1];
        const float x = __uint_as_float((unsigned)v << 16);
        const float a = fabsf(x);
        if (a > 1e20f || (a > 0.f && a < 1e-20f)) weird++;
    }
#pragma unroll
    for (int off = 32; off; off >>= 1) weird += __shfl_xor(weird, off);
    if (t == 0) *flag = (weird < 32) ? 1 : 0;
}

// ---------------------------------------------------------------------------
// Kernel 1: x = embedding[seq] + PE;  Q/K/V = x @ W^T  (f32 to workspace)
// 128 threads (one per output dim) x RROWS=32 token rows: weight float4s
// loaded once per 32 rows, x broadcast from LDS (wave-uniform -> free).
// ---------------------------------------------------------------------------
template <typename T>
__device__ __forceinline__ void qkv_body(
    const int* __restrict__ seq, const T* __restrict__ emb,
    const T* __restrict__ wq, const T* __restrict__ wk, const T* __restrict__ wv,
    float* __restrict__ Q, float* __restrict__ K, float* __restrict__ V)
{
    const int e = threadIdx.x;               // 0..127 output dim
    const int r0 = blockIdx.x * RROWS;
    __shared__ __align__(16) float xs[RROWS][D_MODEL];

    const int i = e >> 1;
    const double denom = pow(10000.0, (double)i / 64.0);
#pragma unroll 4
    for (int r = 0; r < RROWS; ++r) {
        const int row = r0 + r;
        const int s = row & (SEQ - 1);
        const double ang = (double)s / denom;
        const float pe = (float)((e & 1) ? cos(ang) : sin(ang));
        xs[r][e] = tof(emb[(size_t)seq[row] * D_MODEL + e]) + pe;
    }
    __syncthreads();

    const T* wqr = wq + e * D_MODEL;
    const T* wkr = wk + e * D_MODEL;
    const T* wvr = wv + e * D_MODEL;
    float aq[RROWS], ak[RROWS], av[RROWS];
#pragma unroll
    for (int r = 0; r < RROWS; ++r) { aq[r] = 0.f; ak[r] = 0.f; av[r] = 0.f; }

    for (int c = 0; c < 32; ++c) {
        const float q0 = tof(wqr[4*c]), q1 = tof(wqr[4*c+1]), q2 = tof(wqr[4*c+2]), q3 = tof(wqr[4*c+3]);
        const float k0 = tof(wkr[4*c]), k1 = tof(wkr[4*c+1]), k2 = tof(wkr[4*c+2]), k3 = tof(wkr[4*c+3]);
        const float v0 = tof(wvr[4*c]), v1 = tof(wvr[4*c+1]), v2 = tof(wvr[4*c+2]), v3 = tof(wvr[4*c+3]);
#pragma unroll
        for (int r = 0; r < RROWS; ++r) {
            const float4 x4 = *(const float4*)&xs[r][4*c];   // wave-uniform broadcast
            aq[r] += x4.x*q0 + x4.y*q1 + x4.z*q2 + x4.w*q3;
            ak[r] += x4.x*k0 + x4.y*k1 + x4.z*k2 + x4.w*k3;
            av[r] += x4.x*v0 + x4.y*v1 + x4.z*v2 + x4.w*v3;
        }
    }
#pragma unroll
    for (int r = 0; r < RROWS; ++r) {
        const size_t o = (size_t)(r0 + r) * D_MODEL + e;
        Q[o] = aq[r]; K[o] = ak[r]; V[o] = av[r];
    }
}

__global__ __launch_bounds__(128) void qkv_kernel(
    const int* __restrict__ seq, const void* emb,
    const void* wq, const void* wk, const void* wv,
    float* __restrict__ Q, float* __restrict__ K, float* __restrict__ V,
    const int* __restrict__ flag)
{
    if (*flag)
        qkv_body<float>(seq, (const float*)emb, (const float*)wq,
                        (const float*)wk, (const float*)wv, Q, K, V);
    else
        qkv_body<__hip_bfloat16>(seq, (const __hip_bfloat16*)emb, (const __hip_bfloat16*)wq,
                                 (const __hip_bfloat16*)wk, (const __hip_bfloat16*)wv, Q, K, V);
}

// ---------------------------------------------------------------------------
// Kernel 2: attention. Each lane owns TWO q-rows (row0 = qt*128+lane,
// row1 = row0+64): qv[2][32], ov[2][32], m/l in VGPRs. K/V rows are read as
// VMEM broadcast float4 loads (pointer tainted with an opaque zero VGPR so
// the compiler can NOT prove uniformity and regress to out-of-order s_load
// — R6's 13% VALUBusy). vmcnt pipelining hides L2 latency; each K/V row's
// load cost is amortized over 2 q-rows (128 FMA per 16 loads).
// Block = 8 waves k-splitting the causal range; LDS combine at the end.
// No barriers, no LDS in the K-loop. Inf-free softmax as before.
// ---------------------------------------------------------------------------
__global__ __launch_bounds__(512, 2) void attn_kernel(
    const float* __restrict__ Q, const float* __restrict__ K,
    const float* __restrict__ V, float* __restrict__ O)
{
    const int qt = blockIdx.x;              // 0..31
    const int bh = blockIdx.y;              // 0..7
    const size_t base = (size_t)(bh >> 2) * SEQ * D_MODEL + (size_t)(bh & 3) * SEQ * HEAD_DIM;
    const float* Qh = Q + base;
    float*       Oh = O + base;

    int lzero;                               // opaque 0 in a VGPR
    asm volatile("v_mov_b32 %0, 0" : "=v"(lzero));
    const float* Kh = K + base + lzero;      // VGPR-tainted -> VMEM loads
    const float* Vh = V + base + lzero;

    const int tid  = threadIdx.x;
    const int wid  = __builtin_amdgcn_readfirstlane(tid >> 6);
    const int lane = tid & 63;
    const int row0 = qt * QTILE + lane;
    const int row1 = row0 + 64;

    float qv0[32], qv1[32];
#pragma unroll
    for (int j4 = 0; j4 < 8; ++j4) {
        const float4 a = *(const float4*)(Qh + (size_t)row0 * HEAD_DIM + 4 * j4);
        const float4 b = *(const float4*)(Qh + (size_t)row1 * HEAD_DIM + 4 * j4);
        qv0[4*j4] = a.x; qv0[4*j4+1] = a.y; qv0[4*j4+2] = a.z; qv0[4*j4+3] = a.w;
        qv1[4*j4] = b.x; qv1[4*j4+1] = b.y; qv1[4*j4+2] = b.z; qv1[4*j4+3] = b.w;
    }

    float ov0[32], ov1[32];
#pragma unroll
    for (int j = 0; j < 32; ++j) { ov0[j] = 0.f; ov1[j] = 0.f; }
    float m0 = 0.f, l0 = 0.f, m1 = 0.f, l1 = 0.f;
    const float scale = 0.17677669529663687f;   // 1/sqrt(32)

    const int totalK = (qt + 1) * QTILE;        // causal bound for this q-tile
    const int share  = totalK >> 3;             // per-wave range = (qt+1)*16
    const int kbeg   = wid * share;
    const int kend   = kbeg + share;

    for (int k0 = kbeg; k0 < kend; k0 += CHUNK) {
        float p0[CHUNK], p1[CHUNK];
        float cm0 = m0, cm1 = m1;
#pragma unroll
        for (int i = 0; i < CHUNK; ++i) {
            const int k = k0 + i;
            const float* kr = Kh + (size_t)k * HEAD_DIM;
            float s0 = 0.f, s1 = 0.f;
#pragma unroll
            for (int j4 = 0; j4 < 8; ++j4) {
                const float4 kk = *(const float4*)(kr + 4 * j4);
                s0 += qv0[4*j4]*kk.x + qv0[4*j4+1]*kk.y + qv0[4*j4+2]*kk.z + qv0[4*j4+3]*kk.w;
                s1 += qv1[4*j4]*kk.x + qv1[4*j4+1]*kk.y + qv1[4*j4+2]*kk.z + qv1[4*j4+3]*kk.w;
            }
            s0 = fabsf(s0) * scale;
            s1 = fabsf(s1) * scale;
            p0[i] = (k <= row0) ? s0 : -1.f;    // causal mask, head-space
            p1[i] = (k <= row1) ? s1 : -1.f;
            cm0 = fmaxf(cm0, p0[i]);
            cm1 = fmaxf(cm1, p1[i]);
        }
        // branchless rescale (alpha = 1 exactly when max unchanged)
        const float a0 = __expf(m0 - cm0);
        const float a1 = __expf(m1 - cm1);
        l0 *= a0; l1 *= a1; m0 = cm0; m1 = cm1;
#pragma unroll
        for (int j = 0; j < 32; ++j) { ov0[j] *= a0; ov1[j] *= a1; }
#pragma unroll
        for (int i = 0; i < CHUNK; ++i) {
            const int k = k0 + i;
            const float* vr = Vh + (size_t)k * HEAD_DIM;
            const float e0 = (p0[i] >= 0.f) ? __expf(p0[i] - m0) : 0.f;
            const float e1 = (p1[i] >= 0.f) ? __expf(p1[i] - m1) : 0.f;
            l0 += e0; l1 += e1;
#pragma unroll
            for (int j4 = 0; j4 < 8; ++j4) {
                const float4 vv = *(const float4*)(vr + 4 * j4);
                ov0[4*j4]   += e0 * vv.x; ov0[4*j4+1] += e0 * vv.y;
                ov0[4*j4+2] += e0 * vv.z; ov0[4*j4+3] += e0 * vv.w;
                ov1[4*j4]   += e1 * vv.x; ov1[4*j4+1] += e1 * vv.y;
                ov1[4*j4+2] += e1 * vv.z; ov1[4*j4+3] += e1 * vv.w;
            }
        }
    }

    // combine the 8 per-wave partials; 4 passes of 8 dims; LDS = 40KB
    __shared__ float part[NW][QTILE][10];
#pragma unroll
    for (int pass = 0; pass < 4; ++pass) {
        __syncthreads();
#pragma unroll
        for (int j = 0; j < 8; ++j) {
            part[wid][lane][j]      = ov0[pass * 8 + j];
            part[wid][lane + 64][j] = ov1[pass * 8 + j];
        }
        part[wid][lane][8]      = m0; part[wid][lane][9]      = l0;
        part[wid][lane + 64][8] = m1; part[wid][lane + 64][9] = l1;
        __syncthreads();
        {
            const int r = tid >> 3;        // 0..63 -> rows r and r+64
            const int j = tid & 7;
#pragma unroll
            for (int half = 0; half < 2; ++half) {
                const int rr = r + half * 64;
                float M = 0.f;
#pragma unroll
                for (int w = 0; w < NW; ++w) M = fmaxf(M, part[w][rr][8]);
                float lsum = 0.f, osum = 0.f;
#pragma unroll
                for (int w = 0; w < NW; ++w) {
                    const float a = __expf(part[w][rr][8] - M);
                    lsum += a * part[w][rr][9];
                    osum += a * part[w][rr][j];
                }
                Oh[(size_t)(qt * QTILE + rr) * HEAD_DIM + pass * 8 + j] = osum / lsum;
            }
        }
    }
}

// ---------------------------------------------------------------------------
// Kernel 3: out = att @ Wo^T  (32-row weight reuse)
// ---------------------------------------------------------------------------
template <typename T>
__device__ __forceinline__ void out_proj_body(
    const float* __restrict__ att, const T* __restrict__ wo, T* __restrict__ out)
{
    const int e = threadIdx.x;
    const int r0 = blockIdx.x * RROWS;
    __shared__ __align__(16) float xs[RROWS][D_MODEL];
#pragma unroll 4
    for (int r = 0; r < RROWS; ++r)
        xs[r][e] = att[(size_t)(r0 + r) * D_MODEL + e];
    __syncthreads();

    const T* wr = wo + e * D_MODEL;
    float acc[RROWS];
#pragma unroll
    for (int r = 0; r < RROWS; ++r) acc[r] = 0.f;
    for (int c = 0; c < 32; ++c) {
        const float w0 = tof(wr[4*c]), w1 = tof(wr[4*c+1]), w2 = tof(wr[4*c+2]), w3 = tof(wr[4*c+3]);
#pragma unroll
        for (int r = 0; r < RROWS; ++r) {
            const float4 x4 = *(const float4*)&xs[r][4*c];
            acc[r] += x4.x*w0 + x4.y*w1 + x4.z*w2 + x4.w*w3;
        }
    }
#pragma unroll
    for (int r = 0; r < RROWS; ++r)
        storef(out, (size_t)(r0 + r) * D_MODEL + e, acc[r]);
}

__global__ __launch_bounds__(128) void out_proj_kernel(
    const float* __restrict__ att, const void* wo, void* out,
    const int* __restrict__ flag)
{
    if (*flag)
        out_proj_body<float>(att, (const float*)wo, (float*)out);
    else
        out_proj_body<__hip_bfloat16>(att, (const __hip_bfloat16*)wo, (__hip_bfloat16*)out);
}

extern "C" void kernel_launch(void* const* d_in, const int* in_sizes, int n_in,
                              void* d_out, int out_size, void* d_ws, size_t ws_size,
                              hipStream_t stream) {
    const int* seq = (const int*)d_in[0];
    const void* emb = d_in[1];
    const void* wq  = d_in[2];
    const void* wk  = d_in[3];
    const void* wv  = d_in[4];
    const void* wo  = d_in[5];

    const size_t N = (size_t)BATCH * SEQ * D_MODEL;   // 1,048,576
    int*   flag = (int*)d_ws;
    float* Q = (float*)((char*)d_ws + 256);
    float* K = Q + N;
    float* V = K + N;
    float* A = Q;   // alias: each attn block reads only its own Q rows first

    detect_kernel<<<dim3(1), dim3(64), 0, stream>>>((const unsigned short*)wq, flag);
    qkv_kernel<<<dim3(BATCH * SEQ / RROWS), dim3(128), 0, stream>>>(seq, emb, wq, wk, wv, Q, K, V, flag);
    attn_kernel<<<dim3(SEQ / QTILE, BATCH * NUM_HEAD), dim3(512), 0, stream>>>(Q, K, V, A);
    out_proj_kernel<<<dim3(BATCH * SEQ / RROWS), dim3(128), 0, stream>>>(A, wo, d_out, flag);
}

// Round 8
// 702.832 us; speedup vs baseline: 3.9064x; 3.9064x over previous
//
#include <hip/hip_runtime.h>
#include <hip/hip_bf16.h>
#include <cmath>

#define D_MODEL 128
#define NUM_HEAD 4
#define HEAD_DIM 32
#define SEQ 4096
#define BATCH 2
#define QTILE 64   // q-rows per tile (one per lane, G=1 -> no spill)
#define NW 8       // waves per attention block (k-split factor)
#define CHUNK 8    // k's per softmax-rescale chunk; (qt+1)*8 is divisible by 8
#define RROWS 32   // token rows per projection block

__device__ __forceinline__ float tof(float x) { return x; }
__device__ __forceinline__ float tof(__hip_bfloat16 x) { return __bfloat162float(x); }
__device__ __forceinline__ void storef(float* p, size_t i, float v) { p[i] = v; }
__device__ __forceinline__ void storef(__hip_bfloat16* p, size_t i, float v) { p[i] = __float2bfloat16(v); }

// ---------------------------------------------------------------------------
// Kernel 0: dtype detector (f32 vs bf16 inputs), unchanged (passes since R3).
// ---------------------------------------------------------------------------
__global__ void detect_kernel(const unsigned short* __restrict__ w, int* __restrict__ flag)
{
    const int t = threadIdx.x;   // 64 threads
    int weird = 0;
#pragma unroll
    for (int j = 0; j < 4; ++j) {
        const unsigned short v = w[(t * 4 + j) * 2 + 1];
        const float x = __uint_as_float((unsigned)v << 16);
        const float a = fabsf(x);
        if (a > 1e20f || (a > 0.f && a < 1e-20f)) weird++;
    }
#pragma unroll
    for (int off = 32; off; off >>= 1) weird += __shfl_xor(weird, off);
    if (t == 0) *flag = (weird < 32) ? 1 : 0;
}

// ---------------------------------------------------------------------------
// Kernel 1: x = embedding[seq] + PE;  Q/K/V = x @ W^T  (f32 to workspace)
// ---------------------------------------------------------------------------
template <typename T>
__device__ __forceinline__ void qkv_body(
    const int* __restrict__ seq, const T* __restrict__ emb,
    const T* __restrict__ wq, const T* __restrict__ wk, const T* __restrict__ wv,
    float* __restrict__ Q, float* __restrict__ K, float* __restrict__ V)
{
    const int e = threadIdx.x;               // 0..127 output dim
    const int r0 = blockIdx.x * RROWS;
    __shared__ __align__(16) float xs[RROWS][D_MODEL];

    const int i = e >> 1;
    const double inv_denom = 1.0 / pow(10000.0, (double)i / 64.0);  // once/thread
#pragma unroll 4
    for (int r = 0; r < RROWS; ++r) {
        const int row = r0 + r;
        const int s = row & (SEQ - 1);
        const double ang = (double)s * inv_denom;
        const float pe = (float)((e & 1) ? cos(ang) : sin(ang));
        xs[r][e] = tof(emb[(size_t)seq[row] * D_MODEL + e]) + pe;
    }
    __syncthreads();

    const T* wqr = wq + e * D_MODEL;
    const T* wkr = wk + e * D_MODEL;
    const T* wvr = wv + e * D_MODEL;
    float aq[RROWS], ak[RROWS], av[RROWS];
#pragma unroll
    for (int r = 0; r < RROWS; ++r) { aq[r] = 0.f; ak[r] = 0.f; av[r] = 0.f; }

    for (int c = 0; c < 32; ++c) {
        const float q0 = tof(wqr[4*c]), q1 = tof(wqr[4*c+1]), q2 = tof(wqr[4*c+2]), q3 = tof(wqr[4*c+3]);
        const float k0 = tof(wkr[4*c]), k1 = tof(wkr[4*c+1]), k2 = tof(wkr[4*c+2]), k3 = tof(wkr[4*c+3]);
        const float v0 = tof(wvr[4*c]), v1 = tof(wvr[4*c+1]), v2 = tof(wvr[4*c+2]), v3 = tof(wvr[4*c+3]);
#pragma unroll
        for (int r = 0; r < RROWS; ++r) {
            const float4 x4 = *(const float4*)&xs[r][4*c];   // wave-uniform broadcast
            aq[r] += x4.x*q0 + x4.y*q1 + x4.z*q2 + x4.w*q3;
            ak[r] += x4.x*k0 + x4.y*k1 + x4.z*k2 + x4.w*k3;
            av[r] += x4.x*v0 + x4.y*v1 + x4.z*v2 + x4.w*v3;
        }
    }
#pragma unroll
    for (int r = 0; r < RROWS; ++r) {
        const size_t o = (size_t)(r0 + r) * D_MODEL + e;
        Q[o] = aq[r]; K[o] = ak[r]; V[o] = av[r];
    }
}

__global__ __launch_bounds__(128) void qkv_kernel(
    const int* __restrict__ seq, const void* emb,
    const void* wq, const void* wk, const void* wv,
    float* __restrict__ Q, float* __restrict__ K, float* __restrict__ V,
    const int* __restrict__ flag)
{
    if (*flag)
        qkv_body<float>(seq, (const float*)emb, (const float*)wq,
                        (const float*)wk, (const float*)wv, Q, K, V);
    else
        qkv_body<__hip_bfloat16>(seq, (const __hip_bfloat16*)emb, (const __hip_bfloat16*)wq,
                                 (const __hip_bfloat16*)wk, (const __hip_bfloat16*)wv, Q, K, V);
}

// ---------------------------------------------------------------------------
// Kernel 2: attention. G=1: each lane owns ONE q-row (qv[32], ov[32], m, l in
// VGPRs, ~90 live -> no spill; R7's G=2 spilled at 128-cap, 1.9GB scratch).
// K/V rows via VMEM broadcast float4 loads (pointer tainted with opaque zero
// VGPR so the compiler can't regress to out-of-order s_load, R6's 13% VALU).
// Perfect balance: block bx processes q-tiles bx and 63-bx sequentially ->
// every block does exactly 65 chunk-iterations per wave. Per-wave k-share =
// (qt+1)*8, exactly divisible by CHUNK=8 -> no clamp logic.
// 8 waves k-split; 20KB LDS combine per tile. Inf-free softmax throughout.
// ---------------------------------------------------------------------------
__device__ __forceinline__ void attn_tile(
    int qt, int wid, int lane, int tid,
    const float* __restrict__ Qh, const float* __restrict__ Kh,
    const float* __restrict__ Vh, float* __restrict__ Oh,
    float (*part)[QTILE][10])
{
    const int row = qt * QTILE + lane;

    float qv[32];
#pragma unroll
    for (int j4 = 0; j4 < 8; ++j4) {
        const float4 a = *(const float4*)(Qh + (size_t)row * HEAD_DIM + 4 * j4);
        qv[4*j4] = a.x; qv[4*j4+1] = a.y; qv[4*j4+2] = a.z; qv[4*j4+3] = a.w;
    }

    float ov[32];
#pragma unroll
    for (int j = 0; j < 32; ++j) ov[j] = 0.f;
    float m = 0.f, l = 0.f;
    const float scale = 0.17677669529663687f;   // 1/sqrt(32)

    const int share = (qt + 1) * (QTILE / NW);  // = (qt+1)*8, multiple of CHUNK
    const int kbeg  = wid * share;
    const int kend  = kbeg + share;

    for (int k0 = kbeg; k0 < kend; k0 += CHUNK) {
        float p[CHUNK];
        float cm = m;
#pragma unroll
        for (int i = 0; i < CHUNK; ++i) {
            const int k = k0 + i;
            const float* kr = Kh + (size_t)k * HEAD_DIM;
            float sc = 0.f;
#pragma unroll
            for (int j4 = 0; j4 < 8; ++j4) {
                const float4 kk = *(const float4*)(kr + 4 * j4);
                sc += qv[4*j4]*kk.x + qv[4*j4+1]*kk.y + qv[4*j4+2]*kk.z + qv[4*j4+3]*kk.w;
            }
            sc = fabsf(sc) * scale;
            p[i] = (k <= row) ? sc : -1.f;      // causal mask (head-space)
            cm = fmaxf(cm, p[i]);
        }
        const float alpha = __expf(m - cm);     // == 1 when max unchanged
        l *= alpha; m = cm;
#pragma unroll
        for (int j = 0; j < 32; ++j) ov[j] *= alpha;
#pragma unroll
        for (int i = 0; i < CHUNK; ++i) {
            const int k = k0 + i;
            const float* vr = Vh + (size_t)k * HEAD_DIM;
            const float e0 = (p[i] >= 0.f) ? __expf(p[i] - m) : 0.f;
            l += e0;
#pragma unroll
            for (int j4 = 0; j4 < 8; ++j4) {
                const float4 vv = *(const float4*)(vr + 4 * j4);
                ov[4*j4]   += e0 * vv.x; ov[4*j4+1] += e0 * vv.y;
                ov[4*j4+2] += e0 * vv.z; ov[4*j4+3] += e0 * vv.w;
            }
        }
    }

    // combine the 8 per-wave partials; 4 passes of 8 dims; LDS = 20.5KB
#pragma unroll
    for (int pass = 0; pass < 4; ++pass) {
        __syncthreads();
#pragma unroll
        for (int j = 0; j < 8; ++j) part[wid][lane][j] = ov[pass * 8 + j];
        part[wid][lane][8] = m;
        part[wid][lane][9] = l;
        __syncthreads();
        {
            const int r = tid >> 3;        // 0..63
            const int j = tid & 7;
            float M = 0.f;
#pragma unroll
            for (int w = 0; w < NW; ++w) M = fmaxf(M, part[w][r][8]);
            float lsum = 0.f, osum = 0.f;
#pragma unroll
            for (int w = 0; w < NW; ++w) {
                const float a = __expf(part[w][r][8] - M);
                lsum += a * part[w][r][9];
                osum += a * part[w][r][j];
            }
            Oh[(size_t)(qt * QTILE + r) * HEAD_DIM + pass * 8 + j] = osum / lsum;
        }
    }
}

__global__ __launch_bounds__(512, 2) void attn_kernel(
    const float* __restrict__ Q, const float* __restrict__ K,
    const float* __restrict__ V, float* __restrict__ O)
{
    const int bx = blockIdx.x;              // 0..31
    const int bh = blockIdx.y;              // 0..7
    const size_t base = (size_t)(bh >> 2) * SEQ * D_MODEL + (size_t)(bh & 3) * SEQ * HEAD_DIM;
    const float* Qh = Q + base;
    float*       Oh = O + base;

    int lzero;                               // opaque 0 in a VGPR
    asm volatile("v_mov_b32 %0, 0" : "=v"(lzero));
    const float* Kh = K + base + lzero;      // VGPR-tainted -> VMEM loads
    const float* Vh = V + base + lzero;

    const int tid  = threadIdx.x;
    const int wid  = __builtin_amdgcn_readfirstlane(tid >> 6);
    const int lane = tid & 63;

    __shared__ float part[NW][QTILE][10];

    attn_tile(bx,      wid, lane, tid, Qh, Kh, Vh, Oh, part);   // work: bx+1
    attn_tile(63 - bx, wid, lane, tid, Qh, Kh, Vh, Oh, part);   // work: 64-bx
}

// ---------------------------------------------------------------------------
// Kernel 3: out = att @ Wo^T  (32-row weight reuse)
// ---------------------------------------------------------------------------
template <typename T>
__device__ __forceinline__ void out_proj_body(
    const float* __restrict__ att, const T* __restrict__ wo, T* __restrict__ out)
{
    const int e = threadIdx.x;
    const int r0 = blockIdx.x * RROWS;
    __shared__ __align__(16) float xs[RROWS][D_MODEL];
#pragma unroll 4
    for (int r = 0; r < RROWS; ++r)
        xs[r][e] = att[(size_t)(r0 + r) * D_MODEL + e];
    __syncthreads();

    const T* wr = wo + e * D_MODEL;
    float acc[RROWS];
#pragma unroll
    for (int r = 0; r < RROWS; ++r) acc[r] = 0.f;
    for (int c = 0; c < 32; ++c) {
        const float w0 = tof(wr[4*c]), w1 = tof(wr[4*c+1]), w2 = tof(wr[4*c+2]), w3 = tof(wr[4*c+3]);
#pragma unroll
        for (int r = 0; r < RROWS; ++r) {
            const float4 x4 = *(const float4*)&xs[r][4*c];
            acc[r] += x4.x*w0 + x4.y*w1 + x4.z*w2 + x4.w*w3;
        }
    }
#pragma unroll
    for (int r = 0; r < RROWS; ++r)
        storef(out, (size_t)(r0 + r) * D_MODEL + e, acc[r]);
}

__global__ __launch_bounds__(128) void out_proj_kernel(
    const float* __restrict__ att, const void* wo, void* out,
    const int* __restrict__ flag)
{
    if (*flag)
        out_proj_body<float>(att, (const float*)wo, (float*)out);
    else
        out_proj_body<__hip_bfloat16>(att, (const __hip_bfloat16*)wo, (__hip_bfloat16*)out);
}

extern "C" void kernel_launch(void* const* d_in, const int* in_sizes, int n_in,
                              void* d_out, int out_size, void* d_ws, size_t ws_size,
                              hipStream_t stream) {
    const int* seq = (const int*)d_in[0];
    const void* emb = d_in[1];
    const void* wq  = d_in[2];
    const void* wk  = d_in[3];
    const void* wv  = d_in[4];
    const void* wo  = d_in[5];

    const size_t N = (size_t)BATCH * SEQ * D_MODEL;   // 1,048,576
    int*   flag = (int*)d_ws;
    float* Q = (float*)((char*)d_ws + 256);
    float* K = Q + N;
    float* V = K + N;
    float* A = Q;   // alias: each attn tile reads only its own Q rows first

    detect_kernel<<<dim3(1), dim3(64), 0, stream>>>((const unsigned short*)wq, flag);
    qkv_kernel<<<dim3(BATCH * SEQ / RROWS), dim3(128), 0, stream>>>(seq, emb, wq, wk, wv, Q, K, V, flag);
    attn_kernel<<<dim3(SEQ / QTILE / 2, BATCH * NUM_HEAD), dim3(512), 0, stream>>>(Q, K, V, A);
    out_proj_kernel<<<dim3(BATCH * SEQ / RROWS), dim3(128), 0, stream>>>(A, wo, d_out, flag);
}